// Round 9
// baseline (445.338 us; speedup 1.0000x reference)
//
#include <hip/hip_runtime.h>

typedef __attribute__((ext_vector_type(8))) short short8;
typedef __attribute__((ext_vector_type(4))) short s16x4;
typedef __attribute__((ext_vector_type(4))) float f32x4;
typedef __attribute__((ext_vector_type(4))) int int4v;
typedef __attribute__((ext_vector_type(2))) unsigned int uint2v;
typedef __attribute__((ext_vector_type(4))) unsigned int uint4v;

#define MFMA16x16x32(a, b, c) __builtin_amdgcn_mfma_f32_16x16x32_bf16((a), (b), (c), 0, 0, 0)

// (1/sqrt(64)) * log2(e): folded into the Q projection epilogue, so the
// attention softmax is x = exp2(st + bias) with bias in {0, -96} (log2 dom).
#define QK_SCALE 0.18033688011112042f

__device__ __forceinline__ unsigned short f2bf(float f) {
  unsigned u = __builtin_bit_cast(unsigned, f);
  u += 0x7fffu + ((u >> 16) & 1u);  // RNE
  return (unsigned short)(u >> 16);
}

__device__ __forceinline__ unsigned cvt_pk(float lo, float hi) {
  unsigned r;
  asm("v_cvt_pk_bf16_f32 %0, %1, %2" : "=v"(r) : "v"(lo), "v"(hi));
  return r;
}

// PV matmul: K=16 bf16 MFMA whose A-fragment (row=lane&15, k=(lane>>4)*4+j)
// exactly matches the in-register P layout produced by swapped QK^T.
__device__ __forceinline__ f32x4 mfma16(s16x4 a, s16x4 b, f32x4 c) {
  f32x4 d;
  asm("v_mfma_f32_16x16x16_bf16 %0, %1, %2, %3" : "=v"(d) : "v"(a), "v"(b), "v"(c));
  return d;
}

// fp32 -> bf16 bulk convert, 8 elems/thread
__global__ __launch_bounds__(256) void prep_bf16(const float* __restrict__ in,
                                                 unsigned short* __restrict__ out) {
  const int i = (blockIdx.x * 256 + threadIdx.x) * 8;
  f32x4 a = *(const f32x4*)(in + i);
  f32x4 b = *(const f32x4*)(in + i + 4);
  uint4v r;
  r[0] = cvt_pk(a[0], a[1]);
  r[1] = cvt_pk(a[2], a[3]);
  r[2] = cvt_pk(b[0], b[1]);
  r[3] = cvt_pk(b[2], b[3]);
  *(uint4v*)(out + i) = r;
}

// mask int32 -> f32 additive bias (0 or -96, log2 domain), 8 elems/thread
__global__ __launch_bounds__(256) void prep_biasf(const int* __restrict__ mask,
                                                  float* __restrict__ bias) {
  const int i = (blockIdx.x * 256 + threadIdx.x) * 8;
  int4v m0 = *(const int4v*)(mask + i);
  int4v m1 = *(const int4v*)(mask + i + 4);
  f32x4 o0, o1;
#pragma unroll
  for (int j = 0; j < 4; ++j) o0[j] = (m0[j] == 0) ? -96.0f : 0.0f;
#pragma unroll
  for (int j = 0; j < 4; ++j) o1[j] = (m1[j] == 0) ? -96.0f : 0.0f;
  *(f32x4*)(bias + i) = o0;
  *(f32x4*)(bias + i + 4) = o1;
}

// C[M,N] = (A[M,K] @ B[N,K]^T + bias) * scl; A,B bf16; fp32 accum.
// Reg-prefetched staging (T14): loads for k+1 issued before compute of k.
// EPI 0: bf16 out, [B,H,S,D] layout (m=b*2048+s, n=h*64+d), bias[n]  (Q/K proj)
// EPI 1: bf16 out, [B,H,D,S] layout (m=h*64+d, n=b*2048+s), bias[m]  (V proj, swapped)
// EPI 2: f32 out, plain row-major [M,N], bias[n]                     (final proj)
template <int EPI>
__global__ __launch_bounds__(256) void gemm_bt(
    const unsigned short* __restrict__ A, const unsigned short* __restrict__ B,
    const float* __restrict__ bias, void* __restrict__ out,
    int M, int N, int K, float scl) {
  __shared__ unsigned short Asm[128][72];
  __shared__ unsigned short Bsm[128][72];
  const int tid = threadIdx.x;
  const int lane = tid & 63;
  const int wid = tid >> 6;
  const int wr = wid >> 1, wc = wid & 1;
  const int mbase = blockIdx.y * 128, nbase = blockIdx.x * 128;
  const int srow = tid >> 3, scol = (tid & 7) << 3;  // r-th row adds 32

  f32x4 acc[4][4] = {};

  short8 areg[4], breg[4];
#pragma unroll
  for (int r = 0; r < 4; ++r) {
    areg[r] = *(const short8*)(A + (size_t)(mbase + srow + 32 * r) * K + scol);
    breg[r] = *(const short8*)(B + (size_t)(nbase + srow + 32 * r) * K + scol);
  }

  for (int k0 = 0; k0 < K; k0 += 64) {
#pragma unroll
    for (int r = 0; r < 4; ++r) {
      *(short8*)&Asm[srow + 32 * r][scol] = areg[r];
      *(short8*)&Bsm[srow + 32 * r][scol] = breg[r];
    }
    if (k0 + 64 < K) {
#pragma unroll
      for (int r = 0; r < 4; ++r) {
        areg[r] = *(const short8*)(A + (size_t)(mbase + srow + 32 * r) * K + k0 + 64 + scol);
        breg[r] = *(const short8*)(B + (size_t)(nbase + srow + 32 * r) * K + k0 + 64 + scol);
      }
    }
    __syncthreads();
#pragma unroll
    for (int ks = 0; ks < 2; ++ks) {
      const int kk = ks * 32 + (lane >> 4) * 8;
      short8 af[4], bfv[4];
#pragma unroll
      for (int t = 0; t < 4; ++t) {
        af[t] = *(const short8*)&Asm[wr * 64 + t * 16 + (lane & 15)][kk];
        bfv[t] = *(const short8*)&Bsm[wc * 64 + t * 16 + (lane & 15)][kk];
      }
#pragma unroll
      for (int tm = 0; tm < 4; ++tm)
#pragma unroll
        for (int tn = 0; tn < 4; ++tn)
          acc[tm][tn] = MFMA16x16x32(af[tm], bfv[tn], acc[tm][tn]);
    }
    __syncthreads();
  }

  float bn[4];
  if (EPI == 0 || EPI == 2) {
#pragma unroll
    for (int tn = 0; tn < 4; ++tn)
      bn[tn] = bias[nbase + wc * 64 + tn * 16 + (lane & 15)];
  }
  float bm[4][4];
  if (EPI == 1) {
#pragma unroll
    for (int tm = 0; tm < 4; ++tm)
#pragma unroll
      for (int i = 0; i < 4; ++i)
        bm[tm][i] = bias[mbase + wr * 64 + tm * 16 + (lane >> 4) * 4 + i];
  }
#pragma unroll
  for (int tm = 0; tm < 4; ++tm) {
#pragma unroll
    for (int i = 0; i < 4; ++i) {
      const int m = mbase + wr * 64 + tm * 16 + (lane >> 4) * 4 + i;
#pragma unroll
      for (int tn = 0; tn < 4; ++tn) {
        const int n = nbase + wc * 64 + tn * 16 + (lane & 15);
        const float v = (acc[tm][tn][i] + (EPI == 1 ? bm[tm][i] : bn[tn])) * scl;
        if (EPI == 0) {
          const size_t idx =
              (((size_t)(m >> 11) * 16 + (n >> 6)) * 2048 + (m & 2047)) * 64 + (n & 63);
          ((unsigned short*)out)[idx] = f2bf(v);
        } else if (EPI == 1) {
          const size_t idx =
              (((size_t)(n >> 11) * 16 + (m >> 6)) * 64 + (m & 63)) * 2048 + (n & 2047);
          ((unsigned short*)out)[idx] = f2bf(v);
        } else {
          ((float*)out)[(size_t)m * N + n] = v;
        }
      }
    }
  }
}

// Flash attention. 256 threads = 4 waves, 128 q-rows/block, KV tiles of 64.
// Single-barrier double-buffered pipeline: compute tile t from padded LDS
// buf while tile t+1 sits in registers and t+2's loads are in flight.
// Mask enters as f32 additive bias (0/-96, log2 domain), loaded at iter top
// and added AFTER the QK cluster (load latency covered by MFMA). P stays in
// registers and feeds PV via 16x16x16 MFMA. XCD-swizzled grid.
__global__ __launch_bounds__(256, 4) void attn_fused(
    const unsigned short* __restrict__ Qh, const unsigned short* __restrict__ Kh,
    const unsigned short* __restrict__ VT, const float* __restrict__ Biasf,
    unsigned short* __restrict__ Ob) {
  __shared__ unsigned short Kl[2][64][72];
  __shared__ unsigned short Vl[2][64][72];  // VT tile: row = d, col = kv
  const int tid = threadIdx.x, lane = tid & 63, w = tid >> 6;
  const int m = lane & 15, g = lane >> 4;
  // XCD swizzle: all 16 q-tiles of 8 consecutive bh-groups land on one XCD.
  const int wg = ((blockIdx.x & 7) << 7) + (blockIdx.x >> 3);
  const int qt = wg & 15, bh = wg >> 4;
  const int q0 = qt << 7;
  const unsigned short* Qb = Qh + (size_t)bh * (2048 * 64);
  const unsigned short* Kb = Kh + (size_t)bh * (2048 * 64);
  const unsigned short* Vb = VT + (size_t)bh * (64 * 2048);
  const int srow = tid >> 3, scol = (tid & 7) << 3;

  short8 qf[2][2];
#pragma unroll
  for (int ks = 0; ks < 2; ++ks)
#pragma unroll
    for (int tq = 0; tq < 2; ++tq)
      qf[ks][tq] = *(const short8*)(Qb +
          (size_t)(q0 + w * 32 + tq * 16 + m) * 64 + ks * 32 + g * 8);

  const float* brow[2];
#pragma unroll
  for (int tq = 0; tq < 2; ++tq)
    brow[tq] = Biasf + (size_t)(q0 + w * 32 + tq * 16 + m) * 2048 + g * 4;

  f32x4 acc[2][4] = {};
  float l_run[2] = {0.f, 0.f};

  // ---- prologue: tile 0 regs -> LDS buf0; tile 1 regs in flight ----
  short8 kreg[2], vreg[2];
  kreg[0] = *(const short8*)(Kb + (size_t)srow * 64 + scol);
  kreg[1] = *(const short8*)(Kb + (size_t)(srow + 32) * 64 + scol);
  vreg[0] = *(const short8*)(Vb + (size_t)srow * 2048 + scol);
  vreg[1] = *(const short8*)(Vb + (size_t)(srow + 32) * 2048 + scol);
  *(short8*)&Kl[0][srow][scol] = kreg[0];
  *(short8*)&Kl[0][srow + 32][scol] = kreg[1];
  *(short8*)&Vl[0][srow][scol] = vreg[0];
  *(short8*)&Vl[0][srow + 32][scol] = vreg[1];
  kreg[0] = *(const short8*)(Kb + (size_t)(64 + srow) * 64 + scol);
  kreg[1] = *(const short8*)(Kb + (size_t)(64 + srow + 32) * 64 + scol);
  vreg[0] = *(const short8*)(Vb + (size_t)srow * 2048 + 64 + scol);
  vreg[1] = *(const short8*)(Vb + (size_t)(srow + 32) * 2048 + 64 + scol);
  __syncthreads();

  for (int kt = 0; kt < 32; ++kt) {
    const int buf = kt & 1;
    const int kv0 = kt << 6;

    // bias loads for this iter (global; latency covered by the QK cluster)
    f32x4 bini[2][4];
#pragma unroll
    for (int tq = 0; tq < 2; ++tq)
#pragma unroll
      for (int tkv = 0; tkv < 4; ++tkv)
        bini[tq][tkv] = *(const f32x4*)(brow[tq] + kv0 + tkv * 16);

    // S^T = K @ Q^T : rows = kv (64), cols = q (this wave's 32)
    f32x4 st[4][2] = {};
    __builtin_amdgcn_s_setprio(1);
#pragma unroll
    for (int ks = 0; ks < 2; ++ks) {
      const int kk = ks * 32 + g * 8;
      short8 kf[4];
#pragma unroll
      for (int t = 0; t < 4; ++t) kf[t] = *(const short8*)&Kl[buf][t * 16 + m][kk];
#pragma unroll
      for (int tkv = 0; tkv < 4; ++tkv)
#pragma unroll
        for (int tq = 0; tq < 2; ++tq)
          st[tkv][tq] = MFMA16x16x32(kf[tkv], qf[ks][tq], st[tkv][tq]);
    }
    __builtin_amdgcn_s_setprio(0);

    // softmax: x = exp2(st + bias); pack to bf16 pairs, stays in registers
    uint2v pa[2][4];
#pragma unroll
    for (int tq = 0; tq < 2; ++tq) {
      float rsum = l_run[tq];
#pragma unroll
      for (int tkv = 0; tkv < 4; ++tkv) {
        const float x0 = __builtin_amdgcn_exp2f(st[tkv][tq][0] + bini[tq][tkv][0]);
        const float x1 = __builtin_amdgcn_exp2f(st[tkv][tq][1] + bini[tq][tkv][1]);
        const float x2 = __builtin_amdgcn_exp2f(st[tkv][tq][2] + bini[tq][tkv][2]);
        const float x3 = __builtin_amdgcn_exp2f(st[tkv][tq][3] + bini[tq][tkv][3]);
        rsum += (x0 + x1) + (x2 + x3);
        pa[tq][tkv][0] = cvt_pk(x0, x1);
        pa[tq][tkv][1] = cvt_pk(x2, x3);
      }
      l_run[tq] = rsum;
    }

    // O += P @ V via 16x16x16 MFMA; P fragments already in registers.
    asm volatile("s_nop 1");  // VALU(cvt_pk) -> MFMA SrcA hazard guard
    __builtin_amdgcn_s_setprio(1);
#pragma unroll
    for (int tn = 0; tn < 4; ++tn) {
      s16x4 vf[4];
#pragma unroll
      for (int tkv = 0; tkv < 4; ++tkv)
        vf[tkv] = *(const s16x4*)&Vl[buf][tn * 16 + m][tkv * 16 + g * 4];
#pragma unroll
      for (int tm = 0; tm < 2; ++tm)
#pragma unroll
        for (int tkv = 0; tkv < 4; ++tkv)
          acc[tm][tn] = mfma16(__builtin_bit_cast(s16x4, pa[tm][tkv]), vf[tkv], acc[tm][tn]);
    }
    __builtin_amdgcn_s_setprio(0);

    // stage tile t+1 into the other buffer; issue loads for t+2
    if (kt < 31) {
      *(short8*)&Kl[buf ^ 1][srow][scol] = kreg[0];
      *(short8*)&Kl[buf ^ 1][srow + 32][scol] = kreg[1];
      *(short8*)&Vl[buf ^ 1][srow][scol] = vreg[0];
      *(short8*)&Vl[buf ^ 1][srow + 32][scol] = vreg[1];
      if (kt < 30) {
        const int kv2 = (kt + 2) << 6;
        kreg[0] = *(const short8*)(Kb + (size_t)(kv2 + srow) * 64 + scol);
        kreg[1] = *(const short8*)(Kb + (size_t)(kv2 + srow + 32) * 64 + scol);
        vreg[0] = *(const short8*)(Vb + (size_t)srow * 2048 + kv2 + scol);
        vreg[1] = *(const short8*)(Vb + (size_t)(srow + 32) * 2048 + kv2 + scol);
      }
    }
    __syncthreads();
  }

  asm volatile("s_nop 7\ns_nop 7");  // asm-MFMA -> VALU read hazard guard

#pragma unroll
  for (int tm = 0; tm < 2; ++tm) {
    l_run[tm] += __shfl_xor(l_run[tm], 16);
    l_run[tm] += __shfl_xor(l_run[tm], 32);
  }

  const int b = bh >> 4, h = bh & 15;
#pragma unroll
  for (int tm = 0; tm < 2; ++tm) {
#pragma unroll
    for (int i = 0; i < 4; ++i) {
      const float lv = __shfl(l_run[tm], (g << 2) + i);
      const float rl = 1.0f / lv;
      const int q = q0 + w * 32 + tm * 16 + (g << 2) + i;
      unsigned short* orow = Ob + ((size_t)b * 2048 + q) * 1024 + h * 64;
#pragma unroll
      for (int tn = 0; tn < 4; ++tn)
        orow[tn * 16 + m] = f2bf(acc[tm][tn][i] * rl);
    }
  }
}

extern "C" void kernel_launch(void* const* d_in, const int* in_sizes, int n_in,
                              void* d_out, int out_size, void* d_ws, size_t ws_size,
                              hipStream_t stream) {
  const float* q = (const float*)d_in[0];
  const float* k = (const float*)d_in[1];
  const float* v = (const float*)d_in[2];
  const int* mask = (const int*)d_in[3];
  const float* wq = (const float*)d_in[4];
  const float* bq = (const float*)d_in[5];
  const float* wk = (const float*)d_in[6];
  const float* bk = (const float*)d_in[7];
  const float* wv = (const float*)d_in[8];
  const float* bv = (const float*)d_in[9];
  const float* wo = (const float*)d_in[10];
  const float* bo = (const float*)d_in[11];

  char* ws = (char*)d_ws;
  unsigned short* Qh = (unsigned short*)ws;                   // A: 16 MB bf16 [B,H,S,D]
  unsigned short* Kh = (unsigned short*)(ws + (16u << 20));   // B: 16 MB bf16 [B,H,S,D]
  unsigned short* VT = (unsigned short*)(ws + (32u << 20));   // C: 16 MB bf16 [B,H,D,S]
  float* Biasf = (float*)(ws + (48u << 20));                  // D: 16 MB f32 [S,S]
  unsigned short* S = (unsigned short*)(ws + (64u << 20));    // E: 16 MB x-bf16, then Ob
  unsigned short* Ob = S;
  // weight slots alias regions dead at their time of use:
  unsigned short* wqb = Kh;                      // dead once gemm-K writes Kh
  unsigned short* wkb = VT;                      // dead once gemm-V writes VT
  unsigned short* wvb = (unsigned short*)Biasf;  // dead once prep_biasf runs
  unsigned short* wob = Qh;                      // written after attn reads Qh
  // total 80 MiB

  const dim3 blk(256);
  // Q projection (pre-scaled by QK_SCALE so softmax is exp2(st + bias))
  prep_bf16<<<dim3(4096), blk, 0, stream>>>(q, S);
  prep_bf16<<<dim3(512), blk, 0, stream>>>(wq, wqb);
  gemm_bt<0><<<dim3(8, 64), blk, 0, stream>>>(S, wqb, bq, (void*)Qh, 8192, 1024, 1024, QK_SCALE);
  // K projection
  prep_bf16<<<dim3(4096), blk, 0, stream>>>(k, S);
  prep_bf16<<<dim3(512), blk, 0, stream>>>(wk, wkb);
  gemm_bt<0><<<dim3(8, 64), blk, 0, stream>>>(S, wkb, bk, (void*)Kh, 8192, 1024, 1024, 1.0f);
  // V projection swapped: VT = (x@wv^T)^T = wv @ x^T; M=1024, N=8192
  prep_bf16<<<dim3(4096), blk, 0, stream>>>(v, S);
  prep_bf16<<<dim3(512), blk, 0, stream>>>(wv, wvb);
  gemm_bt<1><<<dim3(64, 8), blk, 0, stream>>>(wvb, S, bv, (void*)VT, 1024, 8192, 1024, 1.0f);
  // mask -> f32 additive bias (after V-GEMM so it can overwrite wvb)
  prep_biasf<<<dim3(2048), blk, 0, stream>>>(mask, Biasf);
  // fused attention -> Ob (bf16, [B,S,E]; aliases S)
  attn_fused<<<dim3(1024), blk, 0, stream>>>(Qh, Kh, VT, Biasf, Ob);
  // output projection -> d_out (f32)
  prep_bf16<<<dim3(512), blk, 0, stream>>>(wo, wob);
  gemm_bt<2><<<dim3(8, 64), blk, 0, stream>>>(Ob, wob, bo, d_out, 8192, 1024, 1024, 1.0f);
}

// Round 10
// 296.728 us; speedup vs baseline: 1.5008x; 1.5008x over previous
//
#include <hip/hip_runtime.h>

typedef __attribute__((ext_vector_type(8))) short short8;
typedef __attribute__((ext_vector_type(4))) short s16x4;
typedef __attribute__((ext_vector_type(4))) float f32x4;
typedef __attribute__((ext_vector_type(4))) int int4v;
typedef __attribute__((ext_vector_type(2))) unsigned int uint2v;
typedef __attribute__((ext_vector_type(4))) unsigned int uint4v;

#define MFMA16x16x32(a, b, c) __builtin_amdgcn_mfma_f32_16x16x32_bf16((a), (b), (c), 0, 0, 0)

// (1/sqrt(64)) * log2(e): folded into the Q projection epilogue, so the
// attention softmax is x = exp2(st + bias) with bias in {0, -96} (log2 dom).
#define QK_SCALE 0.18033688011112042f

__device__ __forceinline__ unsigned short f2bf(float f) {
  unsigned u = __builtin_bit_cast(unsigned, f);
  u += 0x7fffu + ((u >> 16) & 1u);  // RNE
  return (unsigned short)(u >> 16);
}

__device__ __forceinline__ unsigned cvt_pk(float lo, float hi) {
  unsigned r;
  asm("v_cvt_pk_bf16_f32 %0, %1, %2" : "=v"(r) : "v"(lo), "v"(hi));
  return r;
}

// PV matmul: K=16 bf16 MFMA whose A-fragment (row=lane&15, k=(lane>>4)*4+j)
// exactly matches the in-register P layout produced by swapped QK^T.
__device__ __forceinline__ f32x4 mfma16(s16x4 a, s16x4 b, f32x4 c) {
  f32x4 d;
  asm("v_mfma_f32_16x16x16_bf16 %0, %1, %2, %3" : "=v"(d) : "v"(a), "v"(b), "v"(c));
  return d;
}

// fp32 -> bf16 bulk convert, 8 elems/thread
__global__ __launch_bounds__(256) void prep_bf16(const float* __restrict__ in,
                                                 unsigned short* __restrict__ out) {
  const int i = (blockIdx.x * 256 + threadIdx.x) * 8;
  f32x4 a = *(const f32x4*)(in + i);
  f32x4 b = *(const f32x4*)(in + i + 4);
  uint4v r;
  r[0] = cvt_pk(a[0], a[1]);
  r[1] = cvt_pk(a[2], a[3]);
  r[2] = cvt_pk(b[0], b[1]);
  r[3] = cvt_pk(b[2], b[3]);
  *(uint4v*)(out + i) = r;
}

// mask int32 -> f32 additive bias (0 or -96, log2 domain), 8 elems/thread
__global__ __launch_bounds__(256) void prep_biasf(const int* __restrict__ mask,
                                                  float* __restrict__ bias) {
  const int i = (blockIdx.x * 256 + threadIdx.x) * 8;
  int4v m0 = *(const int4v*)(mask + i);
  int4v m1 = *(const int4v*)(mask + i + 4);
  f32x4 o0, o1;
#pragma unroll
  for (int j = 0; j < 4; ++j) o0[j] = (m0[j] == 0) ? -96.0f : 0.0f;
#pragma unroll
  for (int j = 0; j < 4; ++j) o1[j] = (m1[j] == 0) ? -96.0f : 0.0f;
  *(f32x4*)(bias + i) = o0;
  *(f32x4*)(bias + i + 4) = o1;
}

// C[M,N] = (A[M,K] @ B[N,K]^T + bias) * scl; A,B bf16; fp32 accum.
// Reg-prefetched staging (T14): loads for k+1 issued before compute of k.
// EPI 0: bf16 out, [B,H,S,D] layout (m=b*2048+s, n=h*64+d), bias[n]  (Q/K proj)
// EPI 1: bf16 out, [B,H,D,S] layout (m=h*64+d, n=b*2048+s), bias[m]  (V proj, swapped)
// EPI 2: f32 out, plain row-major [M,N], bias[n]                     (final proj)
template <int EPI>
__global__ __launch_bounds__(256) void gemm_bt(
    const unsigned short* __restrict__ A, const unsigned short* __restrict__ B,
    const float* __restrict__ bias, void* __restrict__ out,
    int M, int N, int K, float scl) {
  __shared__ unsigned short Asm[128][72];
  __shared__ unsigned short Bsm[128][72];
  const int tid = threadIdx.x;
  const int lane = tid & 63;
  const int wid = tid >> 6;
  const int wr = wid >> 1, wc = wid & 1;
  const int mbase = blockIdx.y * 128, nbase = blockIdx.x * 128;
  const int srow = tid >> 3, scol = (tid & 7) << 3;  // r-th row adds 32

  f32x4 acc[4][4] = {};

  short8 areg[4], breg[4];
#pragma unroll
  for (int r = 0; r < 4; ++r) {
    areg[r] = *(const short8*)(A + (size_t)(mbase + srow + 32 * r) * K + scol);
    breg[r] = *(const short8*)(B + (size_t)(nbase + srow + 32 * r) * K + scol);
  }

  for (int k0 = 0; k0 < K; k0 += 64) {
#pragma unroll
    for (int r = 0; r < 4; ++r) {
      *(short8*)&Asm[srow + 32 * r][scol] = areg[r];
      *(short8*)&Bsm[srow + 32 * r][scol] = breg[r];
    }
    if (k0 + 64 < K) {
#pragma unroll
      for (int r = 0; r < 4; ++r) {
        areg[r] = *(const short8*)(A + (size_t)(mbase + srow + 32 * r) * K + k0 + 64 + scol);
        breg[r] = *(const short8*)(B + (size_t)(nbase + srow + 32 * r) * K + k0 + 64 + scol);
      }
    }
    __syncthreads();
#pragma unroll
    for (int ks = 0; ks < 2; ++ks) {
      const int kk = ks * 32 + (lane >> 4) * 8;
      short8 af[4], bfv[4];
#pragma unroll
      for (int t = 0; t < 4; ++t) {
        af[t] = *(const short8*)&Asm[wr * 64 + t * 16 + (lane & 15)][kk];
        bfv[t] = *(const short8*)&Bsm[wc * 64 + t * 16 + (lane & 15)][kk];
      }
#pragma unroll
      for (int tm = 0; tm < 4; ++tm)
#pragma unroll
        for (int tn = 0; tn < 4; ++tn)
          acc[tm][tn] = MFMA16x16x32(af[tm], bfv[tn], acc[tm][tn]);
    }
    __syncthreads();
  }

  float bn[4];
  if (EPI == 0 || EPI == 2) {
#pragma unroll
    for (int tn = 0; tn < 4; ++tn)
      bn[tn] = bias[nbase + wc * 64 + tn * 16 + (lane & 15)];
  }
  float bm[4][4];
  if (EPI == 1) {
#pragma unroll
    for (int tm = 0; tm < 4; ++tm)
#pragma unroll
      for (int i = 0; i < 4; ++i)
        bm[tm][i] = bias[mbase + wr * 64 + tm * 16 + (lane >> 4) * 4 + i];
  }
#pragma unroll
  for (int tm = 0; tm < 4; ++tm) {
#pragma unroll
    for (int i = 0; i < 4; ++i) {
      const int m = mbase + wr * 64 + tm * 16 + (lane >> 4) * 4 + i;
#pragma unroll
      for (int tn = 0; tn < 4; ++tn) {
        const int n = nbase + wc * 64 + tn * 16 + (lane & 15);
        const float v = (acc[tm][tn][i] + (EPI == 1 ? bm[tm][i] : bn[tn])) * scl;
        if (EPI == 0) {
          const size_t idx =
              (((size_t)(m >> 11) * 16 + (n >> 6)) * 2048 + (m & 2047)) * 64 + (n & 63);
          ((unsigned short*)out)[idx] = f2bf(v);
        } else if (EPI == 1) {
          const size_t idx =
              (((size_t)(n >> 11) * 16 + (m >> 6)) * 64 + (m & 63)) * 2048 + (n & 2047);
          ((unsigned short*)out)[idx] = f2bf(v);
        } else {
          ((float*)out)[(size_t)m * N + n] = v;
        }
      }
    }
  }
}

// Flash attention. 256 threads = 4 waves, 128 q-rows/block, KV tiles of 64.
// Single-barrier double-buffered pipeline: compute tile t from padded LDS
// buf while tile t+1 sits in registers and t+2's loads are in flight.
// Mask enters as f32 additive bias (0/-96, log2 domain), loaded at iter top
// and added AFTER the QK cluster (load latency covered by MFMA). P stays in
// registers and feeds PV via 16x16x16 MFMA. XCD-swizzled grid.
// launch_bounds (256,2): 256 VGPR/wave so the full pipeline state fits
// with zero spill (R9's (256,4) cap caused ~1 GB of scratch traffic).
__global__ __launch_bounds__(256, 2) void attn_fused(
    const unsigned short* __restrict__ Qh, const unsigned short* __restrict__ Kh,
    const unsigned short* __restrict__ VT, const float* __restrict__ Biasf,
    unsigned short* __restrict__ Ob) {
  __shared__ unsigned short Kl[2][64][72];
  __shared__ unsigned short Vl[2][64][72];  // VT tile: row = d, col = kv
  const int tid = threadIdx.x, lane = tid & 63, w = tid >> 6;
  const int m = lane & 15, g = lane >> 4;
  // XCD swizzle: all 16 q-tiles of 8 consecutive bh-groups land on one XCD.
  const int wg = ((blockIdx.x & 7) << 7) + (blockIdx.x >> 3);
  const int qt = wg & 15, bh = wg >> 4;
  const int q0 = qt << 7;
  const unsigned short* Qb = Qh + (size_t)bh * (2048 * 64);
  const unsigned short* Kb = Kh + (size_t)bh * (2048 * 64);
  const unsigned short* Vb = VT + (size_t)bh * (64 * 2048);
  const int srow = tid >> 3, scol = (tid & 7) << 3;

  short8 qf[2][2];
#pragma unroll
  for (int ks = 0; ks < 2; ++ks)
#pragma unroll
    for (int tq = 0; tq < 2; ++tq)
      qf[ks][tq] = *(const short8*)(Qb +
          (size_t)(q0 + w * 32 + tq * 16 + m) * 64 + ks * 32 + g * 8);

  const float* brow[2];
#pragma unroll
  for (int tq = 0; tq < 2; ++tq)
    brow[tq] = Biasf + (size_t)(q0 + w * 32 + tq * 16 + m) * 2048 + g * 4;

  f32x4 acc[2][4] = {};
  float l_run[2] = {0.f, 0.f};

  // ---- prologue: tile 0 regs -> LDS buf0; tile 1 regs in flight ----
  short8 kreg[2], vreg[2];
  kreg[0] = *(const short8*)(Kb + (size_t)srow * 64 + scol);
  kreg[1] = *(const short8*)(Kb + (size_t)(srow + 32) * 64 + scol);
  vreg[0] = *(const short8*)(Vb + (size_t)srow * 2048 + scol);
  vreg[1] = *(const short8*)(Vb + (size_t)(srow + 32) * 2048 + scol);
  *(short8*)&Kl[0][srow][scol] = kreg[0];
  *(short8*)&Kl[0][srow + 32][scol] = kreg[1];
  *(short8*)&Vl[0][srow][scol] = vreg[0];
  *(short8*)&Vl[0][srow + 32][scol] = vreg[1];
  kreg[0] = *(const short8*)(Kb + (size_t)(64 + srow) * 64 + scol);
  kreg[1] = *(const short8*)(Kb + (size_t)(64 + srow + 32) * 64 + scol);
  vreg[0] = *(const short8*)(Vb + (size_t)srow * 2048 + 64 + scol);
  vreg[1] = *(const short8*)(Vb + (size_t)(srow + 32) * 2048 + 64 + scol);
  __syncthreads();

  for (int kt = 0; kt < 32; ++kt) {
    const int buf = kt & 1;
    const int kv0 = kt << 6;

    // bias loads for this iter (global; latency covered by the QK cluster)
    f32x4 bini[2][4];
#pragma unroll
    for (int tq = 0; tq < 2; ++tq)
#pragma unroll
      for (int tkv = 0; tkv < 4; ++tkv)
        bini[tq][tkv] = *(const f32x4*)(brow[tq] + kv0 + tkv * 16);

    // S^T = K @ Q^T : rows = kv (64), cols = q (this wave's 32)
    f32x4 st[4][2] = {};
    __builtin_amdgcn_s_setprio(1);
#pragma unroll
    for (int ks = 0; ks < 2; ++ks) {
      const int kk = ks * 32 + g * 8;
      short8 kf[4];
#pragma unroll
      for (int t = 0; t < 4; ++t) kf[t] = *(const short8*)&Kl[buf][t * 16 + m][kk];
#pragma unroll
      for (int tkv = 0; tkv < 4; ++tkv)
#pragma unroll
        for (int tq = 0; tq < 2; ++tq)
          st[tkv][tq] = MFMA16x16x32(kf[tkv], qf[ks][tq], st[tkv][tq]);
    }
    __builtin_amdgcn_s_setprio(0);

    // softmax: x = exp2(st + bias); pack to bf16 pairs, stays in registers
    uint2v pa[2][4];
#pragma unroll
    for (int tq = 0; tq < 2; ++tq) {
      float rsum = l_run[tq];
#pragma unroll
      for (int tkv = 0; tkv < 4; ++tkv) {
        const float x0 = __builtin_amdgcn_exp2f(st[tkv][tq][0] + bini[tq][tkv][0]);
        const float x1 = __builtin_amdgcn_exp2f(st[tkv][tq][1] + bini[tq][tkv][1]);
        const float x2 = __builtin_amdgcn_exp2f(st[tkv][tq][2] + bini[tq][tkv][2]);
        const float x3 = __builtin_amdgcn_exp2f(st[tkv][tq][3] + bini[tq][tkv][3]);
        rsum += (x0 + x1) + (x2 + x3);
        pa[tq][tkv][0] = cvt_pk(x0, x1);
        pa[tq][tkv][1] = cvt_pk(x2, x3);
      }
      l_run[tq] = rsum;
    }

    // O += P @ V via 16x16x16 MFMA; P fragments already in registers.
    asm volatile("s_nop 1");  // VALU(cvt_pk) -> MFMA SrcA hazard guard
    __builtin_amdgcn_s_setprio(1);
#pragma unroll
    for (int tn = 0; tn < 4; ++tn) {
      s16x4 vf[4];
#pragma unroll
      for (int tkv = 0; tkv < 4; ++tkv)
        vf[tkv] = *(const s16x4*)&Vl[buf][tn * 16 + m][tkv * 16 + g * 4];
#pragma unroll
      for (int tm = 0; tm < 2; ++tm)
#pragma unroll
        for (int tkv = 0; tkv < 4; ++tkv)
          acc[tm][tn] = mfma16(__builtin_bit_cast(s16x4, pa[tm][tkv]), vf[tkv], acc[tm][tn]);
    }
    __builtin_amdgcn_s_setprio(0);

    // stage tile t+1 into the other buffer; issue loads for t+2
    if (kt < 31) {
      *(short8*)&Kl[buf ^ 1][srow][scol] = kreg[0];
      *(short8*)&Kl[buf ^ 1][srow + 32][scol] = kreg[1];
      *(short8*)&Vl[buf ^ 1][srow][scol] = vreg[0];
      *(short8*)&Vl[buf ^ 1][srow + 32][scol] = vreg[1];
      if (kt < 30) {
        const int kv2 = (kt + 2) << 6;
        kreg[0] = *(const short8*)(Kb + (size_t)(kv2 + srow) * 64 + scol);
        kreg[1] = *(const short8*)(Kb + (size_t)(kv2 + srow + 32) * 64 + scol);
        vreg[0] = *(const short8*)(Vb + (size_t)srow * 2048 + kv2 + scol);
        vreg[1] = *(const short8*)(Vb + (size_t)(srow + 32) * 2048 + kv2 + scol);
      }
    }
    __syncthreads();
  }

  asm volatile("s_nop 7\ns_nop 7");  // asm-MFMA -> VALU read hazard guard

#pragma unroll
  for (int tm = 0; tm < 2; ++tm) {
    l_run[tm] += __shfl_xor(l_run[tm], 16);
    l_run[tm] += __shfl_xor(l_run[tm], 32);
  }

  const int b = bh >> 4, h = bh & 15;
#pragma unroll
  for (int tm = 0; tm < 2; ++tm) {
#pragma unroll
    for (int i = 0; i < 4; ++i) {
      const float lv = __shfl(l_run[tm], (g << 2) + i);
      const float rl = 1.0f / lv;
      const int q = q0 + w * 32 + tm * 16 + (g << 2) + i;
      unsigned short* orow = Ob + ((size_t)b * 2048 + q) * 1024 + h * 64;
#pragma unroll
      for (int tn = 0; tn < 4; ++tn)
        orow[tn * 16 + m] = f2bf(acc[tm][tn][i] * rl);
    }
  }
}

extern "C" void kernel_launch(void* const* d_in, const int* in_sizes, int n_in,
                              void* d_out, int out_size, void* d_ws, size_t ws_size,
                              hipStream_t stream) {
  const float* q = (const float*)d_in[0];
  const float* k = (const float*)d_in[1];
  const float* v = (const float*)d_in[2];
  const int* mask = (const int*)d_in[3];
  const float* wq = (const float*)d_in[4];
  const float* bq = (const float*)d_in[5];
  const float* wk = (const float*)d_in[6];
  const float* bk = (const float*)d_in[7];
  const float* wv = (const float*)d_in[8];
  const float* bv = (const float*)d_in[9];
  const float* wo = (const float*)d_in[10];
  const float* bo = (const float*)d_in[11];

  char* ws = (char*)d_ws;
  unsigned short* Qh = (unsigned short*)ws;                   // A: 16 MB bf16 [B,H,S,D]
  unsigned short* Kh = (unsigned short*)(ws + (16u << 20));   // B: 16 MB bf16 [B,H,S,D]
  unsigned short* VT = (unsigned short*)(ws + (32u << 20));   // C: 16 MB bf16 [B,H,D,S]
  float* Biasf = (float*)(ws + (48u << 20));                  // D: 16 MB f32 [S,S]
  unsigned short* S = (unsigned short*)(ws + (64u << 20));    // E: 16 MB x-bf16, then Ob
  unsigned short* Ob = S;
  // weight slots alias regions dead at their time of use:
  unsigned short* wqb = Kh;                      // dead once gemm-K writes Kh
  unsigned short* wkb = VT;                      // dead once gemm-V writes VT
  unsigned short* wvb = (unsigned short*)Biasf;  // dead once prep_biasf runs
  unsigned short* wob = Qh;                      // written after attn reads Qh
  // total 80 MiB

  const dim3 blk(256);
  // Q projection (pre-scaled by QK_SCALE so softmax is exp2(st + bias))
  prep_bf16<<<dim3(4096), blk, 0, stream>>>(q, S);
  prep_bf16<<<dim3(512), blk, 0, stream>>>(wq, wqb);
  gemm_bt<0><<<dim3(8, 64), blk, 0, stream>>>(S, wqb, bq, (void*)Qh, 8192, 1024, 1024, QK_SCALE);
  // K projection
  prep_bf16<<<dim3(4096), blk, 0, stream>>>(k, S);
  prep_bf16<<<dim3(512), blk, 0, stream>>>(wk, wkb);
  gemm_bt<0><<<dim3(8, 64), blk, 0, stream>>>(S, wkb, bk, (void*)Kh, 8192, 1024, 1024, 1.0f);
  // V projection swapped: VT = (x@wv^T)^T = wv @ x^T; M=1024, N=8192
  prep_bf16<<<dim3(4096), blk, 0, stream>>>(v, S);
  prep_bf16<<<dim3(512), blk, 0, stream>>>(wv, wvb);
  gemm_bt<1><<<dim3(64, 8), blk, 0, stream>>>(wvb, S, bv, (void*)VT, 1024, 8192, 1024, 1.0f);
  // mask -> f32 additive bias (after V-GEMM so it can overwrite wvb)
  prep_biasf<<<dim3(2048), blk, 0, stream>>>(mask, Biasf);
  // fused attention -> Ob (bf16, [B,S,E]; aliases S)
  attn_fused<<<dim3(1024), blk, 0, stream>>>(Qh, Kh, VT, Biasf, Ob);
  // output projection -> d_out (f32)
  prep_bf16<<<dim3(512), blk, 0, stream>>>(wo, wob);
  gemm_bt<2><<<dim3(8, 64), blk, 0, stream>>>(Ob, wob, bo, d_out, 8192, 1024, 1024, 1.0f);
}